// Round 9
// baseline (3778.286 us; speedup 1.0000x reference)
//
#include <hip/hip_runtime.h>
#include <cstdint>

#define BATCH   4
#define NPTS    16384
#define NCH     64
#define NPOINT  2048
#define NSAMP   32
#define NBUCK   (NPTS / 16)   // 1024 buckets of 16 points

// output layout (floats), concatenated in reference return order
#define OFF_XYZ  0                                 // new_xyz      (B,S,3)
#define OFF_IDX1 (BATCH*NPOINT*3)                  // new_xyz_idx  (B,S)    as float
#define OFF_FEAT (OFF_IDX1 + BATCH*NPOINT)         // new_features (B,128,S)
#define OFF_IDX3 (OFF_FEAT + BATCH*128*NPOINT)     // idx          (B,S,32) as float

// Scratch (in new_features region of d_out, overwritten later by mlp_kernel):
// interleaved sorted points pts4[b][n] = float4{x, y, z, asfloat(origidx)}.

// Exact float32 squared distance in numpy's evaluation order.
__device__ __forceinline__ float sqd_exact(float dx, float dy, float dz) {
    float a = __fmul_rn(dx, dx);
    float b = __fmul_rn(dy, dy);
    float c = __fmul_rn(dz, dz);
    return __fadd_rn(__fadd_rn(a, b), c);
}

__device__ __forceinline__ int part3(int v) {
    return (v & 1) | ((v & 2) << 2) | ((v & 4) << 4) | ((v & 8) << 6);
}

// Wave64 max of a u64 key held as (hi,lo) u32 pair, via DPP (no LDS).
// Proven bit-exact in R7 (absmax 0). Identity (0,0) valid: keys are
// nonnegative-distance bits in hi.
__device__ __forceinline__ unsigned long long wave_max_u64(unsigned hi, unsigned lo) {
#define STAGE(ctrl, rmask)                                                      \
    {                                                                           \
        unsigned ohi = (unsigned)__builtin_amdgcn_update_dpp(0, (int)hi, ctrl, rmask, 0xf, false); \
        unsigned olo = (unsigned)__builtin_amdgcn_update_dpp(0, (int)lo, ctrl, rmask, 0xf, false); \
        bool take = (ohi > hi) || ((ohi == hi) & (olo > lo));                   \
        hi = take ? ohi : hi;                                                   \
        lo = take ? olo : lo;                                                   \
    }
    STAGE(0x111, 0xf)   // row_shr:1
    STAGE(0x112, 0xf)   // row_shr:2
    STAGE(0x114, 0xf)   // row_shr:4
    STAGE(0x118, 0xf)   // row_shr:8
    STAGE(0x142, 0xa)   // row_bcast:15
    STAGE(0x143, 0xc)   // row_bcast:31
#undef STAGE
    unsigned rhi = (unsigned)__builtin_amdgcn_readlane((int)hi, 63);
    unsigned rlo = (unsigned)__builtin_amdgcn_readlane((int)lo, 63);
    return ((unsigned long long)rhi << 32) | rlo;
}

// ---------------------------------------------------------------------------
// Kernel 0: plain Morton counting sort (R7 revert), interleaved float4 output.
// ---------------------------------------------------------------------------
__global__ __launch_bounds__(1024)
void binsort_kernel(const float* __restrict__ xyz, float* __restrict__ out) {
    const int b = blockIdx.x, t = threadIdx.x, lane = t & 63, wv = t >> 6;
    float4* pts4 = (float4*)(out + OFF_FEAT) + (size_t)b * NPTS;
    const float* xb = xyz + (size_t)b * (NPTS * 3);

    __shared__ int hist[4096];
    __shared__ int wsum[16];
    for (int k = t; k < 4096; k += 1024) hist[k] = 0;
    __syncthreads();

    const int base = t << 4;
    float f[48];
    {
        const float4* v4 = (const float4*)(xb + (size_t)base * 3);
#pragma unroll
        for (int q = 0; q < 12; ++q) {
            float4 v = v4[q];
            f[4*q+0] = v.x; f[4*q+1] = v.y; f[4*q+2] = v.z; f[4*q+3] = v.w;
        }
    }
    int cells[16];
    const float sc = 16.0f / 9.0f;
#pragma unroll
    for (int j = 0; j < 16; ++j) {
        int qx = (int)fminf(fmaxf((f[3*j+0] + 4.5f) * sc, 0.0f), 15.0f);
        int qy = (int)fminf(fmaxf((f[3*j+1] + 4.5f) * sc, 0.0f), 15.0f);
        int qz = (int)fminf(fmaxf((f[3*j+2] + 4.5f) * sc, 0.0f), 15.0f);
        cells[j] = part3(qx) | (part3(qy) << 1) | (part3(qz) << 2);
        atomicAdd(&hist[cells[j]], 1);
    }
    __syncthreads();

    int h0 = hist[4*t], h1 = hist[4*t+1], h2 = hist[4*t+2], h3 = hist[4*t+3];
    int s = h0 + h1 + h2 + h3;
    int ps = s;
#pragma unroll
    for (int off = 1; off <= 32; off <<= 1) {
        int o = __shfl_up(ps, off, 64);
        if (lane >= off) ps += o;
    }
    if (lane == 63) wsum[wv] = ps;
    __syncthreads();
    int wbase = 0;
    for (int w = 0; w < wv; ++w) wbase += wsum[w];
    int excl = wbase + ps - s;
    hist[4*t]   = excl;
    hist[4*t+1] = excl + h0;
    hist[4*t+2] = excl + h0 + h1;
    hist[4*t+3] = excl + h0 + h1 + h2;
    __syncthreads();

#pragma unroll
    for (int j = 0; j < 16; ++j) {
        int pos = atomicAdd(&hist[cells[j]], 1);
        pts4[pos] = make_float4(f[3*j+0], f[3*j+1], f[3*j+2],
                                __int_as_float(base + j));
    }
}

// ---------------------------------------------------------------------------
// Kernel 1: worklist-compacted exact bucket-pruned FPS.
// State: dist[16384] in LDS; points in global (interleaved float4, L2-hot);
// per-owner regs: bbox (6) + cached u64 key. Per iteration:
//   A: exact skip test per bucket -> ballot-compact active ids to worklist.
//   B: 4 threads per active bucket update dist (b128 RMW) and write the
//      bucket key (distbits<<32 | ~origidx; exact min-oi tie combine).
//   C: owners refresh key if active; DPP u64 wave max; lane0 atomicMax into
//      a single LDS u64; barrier; broadcast read -> next center.
// Exactness identical to R2..R8 (absmax 0 lineage).
// ---------------------------------------------------------------------------
__global__ __launch_bounds__(1024)
void fps_kernel(const float* __restrict__ xyz, float* __restrict__ out) {
    const int b = blockIdx.x, t = threadIdx.x, lane = t & 63;
    const float4* __restrict__ pts = (const float4*)(out + OFF_FEAT) + (size_t)b * NPTS;
    const float* __restrict__ xb = xyz + (size_t)b * (NPTS * 3);
    float* oxyz = out + OFF_XYZ  + (size_t)b * (NPOINT * 3);
    float* oidx = out + OFF_IDX1 + (size_t)b * NPOINT;

    __shared__ float s_dist[NPTS];                         // 64 KB
    __shared__ unsigned long long s_key[NBUCK];            // 8 KB
    __shared__ int s_wl[NBUCK];                            // 4 KB
    __shared__ int s_cnt;
    __shared__ unsigned long long s_gkey;

    // init: owner t reads its bucket's 16 points once -> bbox; dist = 1e10.
    float bnx, bxx, bny, bxy, bnz, bxz;
    {
        float4 p0 = pts[t * 16];
        bnx = bxx = p0.x; bny = bxy = p0.y; bnz = bxz = p0.z;
#pragma unroll
        for (int j = 1; j < 16; ++j) {
            float4 p = pts[t * 16 + j];
            bnx = fminf(bnx, p.x); bxx = fmaxf(bxx, p.x);
            bny = fminf(bny, p.y); bxy = fmaxf(bxy, p.y);
            bnz = fminf(bnz, p.z); bxz = fmaxf(bxz, p.z);
        }
        float4 big = make_float4(1e10f, 1e10f, 1e10f, 1e10f);
#pragma unroll
        for (int k = 0; k < 4; ++k)
            *(float4*)&s_dist[t * 16 + k * 4] = big;
    }
    float maxdG = 1e10f;              // forces all buckets active at it=1
    unsigned long long kv = 0;        // cached own-bucket key (set in C when active)
    if (t == 0) { s_cnt = 0; s_gkey = 0ull; }

    float cx = xb[0], cy = xb[1], cz = xb[2];
    if (t == 0) { oxyz[0] = cx; oxyz[1] = cy; oxyz[2] = cz; oidx[0] = 0.0f; }
    __syncthreads();                  // b0: init visible

    for (int it = 1; it < NPOINT; ++it) {
        // ---- A: skip test + worklist push -------------------------------
        float dxl = fmaxf(fmaxf(bnx - cx, cx - bxx), 0.0f);
        float dyl = fmaxf(fmaxf(bny - cy, cy - bxy), 0.0f);
        float dzl = fmaxf(fmaxf(bnz - cz, cz - bxz), 0.0f);
        float bb  = dxl * dxl + dyl * dyl + dzl * dzl;
        bool active = (bb * 0.99999f < maxdG);     // exact (conservative) test
        unsigned long long m = __ballot(active);
        int cntw = (int)__popcll(m);
        if (cntw) {
            int basep = 0;
            if (lane == 0) basep = atomicAdd(&s_cnt, cntw);
            basep = __shfl(basep, 0, 64);
            if (active) {
                int pos = basep + (int)__popcll(m & ((1ull << lane) - 1ull));
                s_wl[pos] = t;
            }
        }
        __syncthreads();                            // b1
        // ---- B: compacted update (4 threads per active bucket) ----------
        if (t == 0) s_gkey = 0ull;                  // clear in b1..b2 window
        const int K = s_cnt;
        const int sub = t & 3;
        for (int w = t >> 2; w < K; w += 256) {
            const int bid = s_wl[w];
            const int p0  = bid * 16 + sub * 4;
            float4 P0 = pts[p0 + 0], P1 = pts[p0 + 1],
                   P2 = pts[p0 + 2], P3 = pts[p0 + 3];
            float4 dv = *(float4*)&s_dist[p0];
            float mv = -1.0f; int bi = 0x7FFFFFFF;
#define UPD(P, DD)                                                              \
            {                                                                   \
                float d  = sqd_exact(__fsub_rn(P.x, cx),                        \
                                     __fsub_rn(P.y, cy),                        \
                                     __fsub_rn(P.z, cz));                       \
                float nd = fminf(DD, d);                                        \
                DD = nd;                                                        \
                int oi = __float_as_int(P.w);                                   \
                bool bet = (nd > mv) || ((nd == mv) & (oi < bi));               \
                mv = bet ? nd : mv;                                             \
                bi = bet ? oi : bi;                                             \
            }
            UPD(P0, dv.x) UPD(P1, dv.y) UPD(P2, dv.z) UPD(P3, dv.w)
#undef UPD
            *(float4*)&s_dist[p0] = dv;
            // exact combine across the 4 sub-threads (consecutive lanes)
#pragma unroll
            for (int off = 1; off <= 2; off <<= 1) {
                float omv = __shfl_xor(mv, off, 64);
                int   obi = __shfl_xor(bi, off, 64);
                bool take = (omv > mv) || ((omv == mv) & (obi < bi));
                mv = take ? omv : mv;
                bi = take ? obi : bi;
            }
            if (sub == 0)
                s_key[bid] = ((unsigned long long)__float_as_uint(mv) << 32)
                           | (unsigned)((~bi) & 0xFFFF);
        }
        __syncthreads();                            // b2
        // ---- C: global argmax over all 1024 bucket keys -----------------
        if (active) {                               // refresh own cached key
            kv = s_key[t];
            maxdG = __uint_as_float((unsigned)(kv >> 32));
        }
        unsigned long long wk = wave_max_u64((unsigned)(kv >> 32), (unsigned)kv);
        if (lane == 0) atomicMax(&s_gkey, wk);
        if (t == 0) s_cnt = 0;                      // clear in b2..b3 window
        __syncthreads();                            // b3
        unsigned long long gk = s_gkey;             // broadcast read
        const int gi = (int)((~(unsigned)gk) & 0xFFFFu);
        cx = xb[gi*3+0]; cy = xb[gi*3+1]; cz = xb[gi*3+2];
        if (t == 0) {
            oxyz[it*3+0] = cx; oxyz[it*3+1] = cy; oxyz[it*3+2] = cz;
            oidx[it] = (float)gi;
        }
    }
}

// ---------------------------------------------------------------------------
// Kernel 2: ball query (unchanged).
// ---------------------------------------------------------------------------
__global__ __launch_bounds__(256)
void ballq_kernel(const float* __restrict__ xyz, float* __restrict__ out) {
    const int b    = blockIdx.y;
    const int t    = threadIdx.x;
    const int lane = t & 63;
    const int wv   = t >> 6;
    const int s    = blockIdx.x * 4 + wv;
    const float* __restrict__ xb = xyz + (size_t)b * (NPTS * 3);

    const float* ctr = out + OFF_XYZ + ((size_t)(b * NPOINT + s)) * 3;
    const float cx = ctr[0], cy = ctr[1], cz = ctr[2];

    __shared__ float sx[256], sy[256], sz[256];
    __shared__ int   lists[4][NSAMP];

    int have = 0;
    for (int tile = 0; tile < NPTS / 256; ++tile) {
        const int pi = tile * 256 + t;
        const float* p = xb + (size_t)pi * 3;
        float ax = p[0], ay = p[1], az = p[2];
        sx[t] = ax; sy[t] = ay; sz[t] = az;
        __syncthreads();
        if (have < NSAMP) {
#pragma unroll
            for (int sub = 0; sub < 4; ++sub) {
                const int li = sub * 64 + lane;
                float d2 = sqd_exact(__fsub_rn(cx, sx[li]),
                                     __fsub_rn(cy, sy[li]),
                                     __fsub_rn(cz, sz[li]));
                bool hit = d2 < 0.04f;
                unsigned long long m = __ballot(hit);
                if (hit) {
                    int pos = have + (int)__popcll(m & ((1ull << lane) - 1ull));
                    if (pos < NSAMP) lists[wv][pos] = tile * 256 + li;
                }
                have += (int)__popcll(m);
                if (have >= NSAMP) break;
            }
        }
        __syncthreads();
    }
    if (lane < NSAMP) {
        int hv = have < NSAMP ? have : NSAMP;
        int v0 = (have > 0) ? lists[wv][0] : 0;
        int v  = (lane < hv) ? lists[wv][lane] : v0;
        out[OFF_IDX3 + ((size_t)(b * NPOINT + s)) * NSAMP + lane] = (float)v;
    }
}

// ---------------------------------------------------------------------------
// Kernel 3: gather + 3-layer MLP + max over samples (unchanged).
// ---------------------------------------------------------------------------
__global__ __launch_bounds__(256)
void mlp_kernel(const float* __restrict__ xyz, const float* __restrict__ feat,
                const float* __restrict__ W1, const float* __restrict__ b1,
                const float* __restrict__ W2, const float* __restrict__ b2,
                const float* __restrict__ W3, const float* __restrict__ b3,
                float* __restrict__ out) {
    const int s = blockIdx.x;
    const int b = blockIdx.y;
    const int t = threadIdx.x;

    __shared__ __align__(16) float Wbuf[64 * 128];
    __shared__ float Xs[67 * 32];
    __shared__ float H1[64 * 32];
    __shared__ float H2[64 * 32];
    __shared__ int   idxs[NSAMP];
    __shared__ float ctr[3];

    if (t < NSAMP) idxs[t] = (int)out[OFF_IDX3 + ((size_t)(b * NPOINT + s)) * NSAMP + t];
    if (t < 3)     ctr[t]  = out[OFF_XYZ + ((size_t)(b * NPOINT + s)) * 3 + t];
    for (int k = t; k < 67 * 64; k += 256) {
        int i = k >> 6, o = k & 63;
        Wbuf[k] = W1[o * 67 + i];
    }
    __syncthreads();

    const float* xb = xyz  + (size_t)b * (NPTS * 3);
    const float* fb = feat + (size_t)b * (NCH * NPTS);
    for (int k = t; k < 67 * 32; k += 256) {
        int i = k >> 5, n = k & 31;
        int ii = idxs[n];
        float v;
        if (i < 3) v = __fsub_rn(xb[(size_t)ii * 3 + i], ctr[i]);
        else       v = fb[(size_t)(i - 3) * NPTS + ii];
        Xs[k] = v;
    }
    __syncthreads();

    const int n  = t & 31;
    const int og = t >> 5;

    {
        const int o0 = og * 8;
        float acc[8] = {0,0,0,0,0,0,0,0};
        for (int i = 0; i < 67; ++i) {
            float x = Xs[i * 32 + n];
            const float4* wp = (const float4*)&Wbuf[i * 64 + o0];
            float4 w0 = wp[0], w1 = wp[1];
            acc[0] += w0.x * x; acc[1] += w0.y * x; acc[2] += w0.z * x; acc[3] += w0.w * x;
            acc[4] += w1.x * x; acc[5] += w1.y * x; acc[6] += w1.z * x; acc[7] += w1.w * x;
        }
#pragma unroll
        for (int k = 0; k < 8; ++k)
            H1[(o0 + k) * 32 + n] = fmaxf(acc[k] + b1[o0 + k], 0.0f);
    }
    __syncthreads();
    for (int k = t; k < 64 * 64; k += 256) {
        int i = k >> 6, o = k & 63;
        Wbuf[k] = W2[o * 64 + i];
    }
    __syncthreads();

    {
        const int o0 = og * 8;
        float acc[8] = {0,0,0,0,0,0,0,0};
        for (int i = 0; i < 64; ++i) {
            float x = H1[i * 32 + n];
            const float4* wp = (const float4*)&Wbuf[i * 64 + o0];
            float4 w0 = wp[0], w1 = wp[1];
            acc[0] += w0.x * x; acc[1] += w0.y * x; acc[2] += w0.z * x; acc[3] += w0.w * x;
            acc[4] += w1.x * x; acc[5] += w1.y * x; acc[6] += w1.z * x; acc[7] += w1.w * x;
        }
#pragma unroll
        for (int k = 0; k < 8; ++k)
            H2[(o0 + k) * 32 + n] = fmaxf(acc[k] + b2[o0 + k], 0.0f);
    }
    __syncthreads();
    for (int k = t; k < 64 * 128; k += 256) {
        int i = k >> 7, o = k & 127;
        Wbuf[k] = W3[o * 64 + i];
    }
    __syncthreads();

    {
        const int o0 = og * 16;
        float acc[16];
#pragma unroll
        for (int k = 0; k < 16; ++k) acc[k] = 0.0f;
        for (int i = 0; i < 64; ++i) {
            float x = H2[i * 32 + n];
            const float4* wp = (const float4*)&Wbuf[i * 128 + o0];
            float4 w0 = wp[0], w1 = wp[1], w2 = wp[2], w3 = wp[3];
            acc[0]  += w0.x * x; acc[1]  += w0.y * x; acc[2]  += w0.z * x; acc[3]  += w0.w * x;
            acc[4]  += w1.x * x; acc[5]  += w1.y * x; acc[6]  += w1.z * x; acc[7]  += w1.w * x;
            acc[8]  += w2.x * x; acc[9]  += w2.y * x; acc[10] += w2.z * x; acc[11] += w2.w * x;
            acc[12] += w3.x * x; acc[13] += w3.y * x; acc[14] += w3.z * x; acc[15] += w3.w * x;
        }
#pragma unroll
        for (int k = 0; k < 16; ++k) {
            float h = fmaxf(acc[k] + b3[o0 + k], 0.0f);
#pragma unroll
            for (int off = 16; off >= 1; off >>= 1)
                h = fmaxf(h, __shfl_xor(h, off, 64));
            if (n == 0)
                out[OFF_FEAT + (size_t)b * 128 * NPOINT + (size_t)(o0 + k) * NPOINT + s] = h;
        }
    }
}

extern "C" void kernel_launch(void* const* d_in, const int* in_sizes, int n_in,
                              void* d_out, int out_size, void* d_ws, size_t ws_size,
                              hipStream_t stream) {
    const float* xyz  = (const float*)d_in[0];
    const float* feat = (const float*)d_in[1];
    const float* W1   = (const float*)d_in[2];
    const float* b1   = (const float*)d_in[3];
    const float* W2   = (const float*)d_in[4];
    const float* b2   = (const float*)d_in[5];
    const float* W3   = (const float*)d_in[6];
    const float* b3   = (const float*)d_in[7];
    float* out = (float*)d_out;

    binsort_kernel<<<BATCH, 1024, 0, stream>>>(xyz, out);
    fps_kernel<<<BATCH, 1024, 0, stream>>>(xyz, out);
    ballq_kernel<<<dim3(NPOINT / 4, BATCH), 256, 0, stream>>>(xyz, out);
    mlp_kernel<<<dim3(NPOINT, BATCH), 256, 0, stream>>>(xyz, feat, W1, b1, W2, b2, W3, b3, out);
}